// Round 5
// baseline (1141.332 us; speedup 1.0000x reference)
//
#include <hip/hip_runtime.h>
#include <hip/hip_bf16.h>

#define Hn   89
#define Tn   120
#define BM   64
#define LDP  104   // LDS row pitch (bf16): 208B -> 16B aligned, 2-way max bank alias
#define NTHR 384   // 6 waves = 6 j-slices; LDS 61,440B/block -> 2 blocks/CU

using bf16   = __bf16;
using bf16x4 = __attribute__((ext_vector_type(4))) __bf16;
using bf16x8 = __attribute__((ext_vector_type(8))) __bf16;
typedef __attribute__((ext_vector_type(4))) float f32x4;

__device__ __forceinline__ f32x4 ld4(const float* p) {   // 4B-aligned 16B load
  f32x4 v; __builtin_memcpy(&v, p, 16); return v;
}
__device__ __forceinline__ float fsig(float x) {
  return __builtin_amdgcn_rcpf(1.f + __builtin_amdgcn_exp2f(-1.44269504f * x));
}
__device__ __forceinline__ float ftanh(float x) {
  return 1.f - 2.f * __builtin_amdgcn_rcpf(1.f + __builtin_amdgcn_exp2f(2.88539008f * x));
}

// Persistent block: 64 batch rows x 120 steps, 6 waves (one per 16-col j-slice).
// 2 blocks/CU -> two INDEPENDENT barrier domains; one block's barrier drain is
// hidden under the other block's compute. Weights live in registers (B-frags);
// k==89 column carries biases (X/H col89 == 1.0). One barrier per step:
// { commit X(t), write h(t) -> buf[t&1]; BAR; issue X(t+1); MFMA + gates }.
__global__ __launch_bounds__(NTHR, 3)
void gru_fused(const float* __restrict__ X,    // [B][T][89]
               const float* __restrict__ Wih,  // [267][89]
               const float* __restrict__ Whh,  // [267][89]
               const float* __restrict__ bih,  // [267]
               const float* __restrict__ bhh,  // [267]
               const float* __restrict__ Wm,   // [32][89]
               const float* __restrict__ bm,   // [32]
               const float* __restrict__ Wo,   // [32]
               const float* __restrict__ bo,   // [1]
               float* __restrict__ Y,          // [B] mscore | [B][32] mmetric
               int Bt)
{
  __shared__ __align__(16) bf16 Xl[2][BM][LDP];
  __shared__ __align__(16) bf16 Hl[2][BM][LDP];
  __shared__ float Ml[BM][32];

  const int tid  = threadIdx.x;
  const int lane = tid & 63;
  const int jt   = tid >> 6;       // j-slice 0..5
  const int l15  = lane & 15;
  const int kg   = lane >> 4;      // 0..3
  const int j    = jt * 16 + l15;  // 0..95; j==89 = constant-1 column
  const bool jok = (j < Hn);
  const size_t brow0 = (size_t)blockIdx.x * BM;

  // ---- weights -> persistent register B-frags; k==89 carries biases ----
  bf16x8 Bf[3][2][3];  // [gate r/z/n][ih/hh][k-tile]
#pragma unroll
  for (int g = 0; g < 3; ++g)
#pragma unroll
    for (int s = 0; s < 2; ++s) {
      const float* W = s ? Whh : Wih;
#pragma unroll
      for (int kt = 0; kt < 3; ++kt) {
        bf16x8 f;
        const int k0 = kt * 32 + kg * 8;
#pragma unroll
        for (int e = 0; e < 8; ++e) {
          const int k = k0 + e;
          float v = 0.f;
          if (jok) {
            if (k < Hn) v = W[(size_t)(g * Hn + j) * Hn + k];
            else if (k == Hn) {           // pairs with the 1.0 at col 89
              if (g < 2) v = s ? 0.f : (bih[g * Hn + j] + bhh[g * Hn + j]);
              else       v = s ? bhh[2 * Hn + j] : bih[2 * Hn + j];
            }
          }
          f[e] = (bf16)v;
        }
        Bf[g][s][kt] = f;
      }
    }

  // ---- X staging: 64 rows x 23 f32x4 chunks (chunk 22 = {x88,1,0,0}) ----
  int soff[4], loff[4];
  bool val[4], lst[4];
#pragma unroll
  for (int i = 0; i < 4; ++i) {
    const int p = tid + i * NTHR;        // 0..1535; 1472 used
    const int r = p / 23, s = p - r * 23;
    val[i]  = (p < BM * 23);
    lst[i]  = (s == 22);
    soff[i] = r * (Tn * Hn) + s * 4;
    loff[i] = r * LDP + s * 4;
  }
  const float* Xb2 = X + brow0 * (size_t)(Tn * Hn);
  f32x4 pa[4];

  auto issue = [&](int tHv) {
#pragma unroll
    for (int i = 0; i < 4; ++i) {
      if (val[i]) {
        if (lst[i]) { f32x4 v = {Xb2[soff[i] + tHv], 1.0f, 0.f, 0.f}; pa[i] = v; }
        else          pa[i] = ld4(Xb2 + soff[i] + tHv);
      }
    }
  };

  // ---- init pads (once): H col89=1.0, cols90..95=0; X cols92..95=0 ----
  if (tid < 2 * BM) {
    const int bb = tid >> 6, r = tid & (BM - 1);
    Hl[bb][r][89] = (bf16)1.0f;
#pragma unroll
    for (int c = 90; c < 96; ++c) Hl[bb][r][c] = (bf16)0.f;
#pragma unroll
    for (int c = 92; c < 96; ++c) Xl[bb][r][c] = (bf16)0.f;
  }

  float hold[4][4];
#pragma unroll
  for (int mt = 0; mt < 4; ++mt)
#pragma unroll
    for (int q = 0; q < 4; ++q) hold[mt][q] = 0.f;

  bf16*       hwb = &Hl[0][0][0] + (kg * 4) * LDP + j;
  const bf16* xrb = &Xl[0][0][0] + l15 * LDP + kg * 8;
  const bf16* hrb = &Hl[0][0][0] + l15 * LDP + kg * 8;
  const int bufo = BM * LDP;

  issue(0);
  int tH = 0;
  for (int t = 0; t < Tn; ++t) {
    const int b = t & 1;
    // ---- commit X(t) regs -> buf b ----
#pragma unroll
    for (int i = 0; i < 4; ++i) {
      if (val[i]) {
        bf16x4 w;
        w[0] = (bf16)pa[i][0]; w[1] = (bf16)pa[i][1];
        w[2] = (bf16)pa[i][2]; w[3] = (bf16)pa[i][3];
        *(bf16x4*)(&Xl[b][0][0] + loff[i]) = w;
      }
    }
    // ---- write h(t) -> buf b (h(0)=0) ----
    if (jok) {
      bf16* hw = hwb + b * bufo;
#pragma unroll
      for (int mt = 0; mt < 4; ++mt)
#pragma unroll
        for (int q = 0; q < 4; ++q)
          hw[(mt * 16 + q) * LDP] = (bf16)hold[mt][q];
    }
    __syncthreads();
    tH += Hn;
    if (t + 1 < Tn) issue(tH);   // loads fly under this step's compute

    // ---- consume buf b: MFMA + gates ----
    const bf16* xr = xrb + b * bufo;
    const bf16* hr = hrb + b * bufo;
#pragma unroll
    for (int mt = 0; mt < 4; ++mt) {
      f32x4 ar = {0,0,0,0}, az = {0,0,0,0}, ain = {0,0,0,0}, ahn = {0,0,0,0};
#pragma unroll
      for (int kt = 0; kt < 3; ++kt) {
        const bf16x8 ax = *(const bf16x8*)(xr + mt * 16 * LDP + kt * 32);
        const bf16x8 ah = *(const bf16x8*)(hr + mt * 16 * LDP + kt * 32);
        ar  = __builtin_amdgcn_mfma_f32_16x16x32_bf16(ax, Bf[0][0][kt], ar, 0, 0, 0);
        ar  = __builtin_amdgcn_mfma_f32_16x16x32_bf16(ah, Bf[0][1][kt], ar, 0, 0, 0);
        az  = __builtin_amdgcn_mfma_f32_16x16x32_bf16(ax, Bf[1][0][kt], az, 0, 0, 0);
        az  = __builtin_amdgcn_mfma_f32_16x16x32_bf16(ah, Bf[1][1][kt], az, 0, 0, 0);
        ain = __builtin_amdgcn_mfma_f32_16x16x32_bf16(ax, Bf[2][0][kt], ain, 0, 0, 0);
        ahn = __builtin_amdgcn_mfma_f32_16x16x32_bf16(ah, Bf[2][1][kt], ahn, 0, 0, 0);
      }
#pragma unroll
      for (int q = 0; q < 4; ++q) {
        const float r_ = fsig(ar[q]);
        const float z_ = fsig(az[q]);
        const float n_ = ftanh(ain[q] + r_ * ahn[q]);
        hold[mt][q] = n_ + z_ * (hold[mt][q] - n_);
      }
    }
  }

  // ---- final h -> buf0 (t=119 consumed buf1; buf0 free) ----
  if (jok) {
#pragma unroll
    for (int mt = 0; mt < 4; ++mt)
#pragma unroll
      for (int q = 0; q < 4; ++q)
        hwb[(mt * 16 + q) * LDP] = (bf16)hold[mt][q];
  }
  __syncthreads();

  // ---- epilogue: metric_fc (89->32, sigmoid), output_fc (32->1, sigmoid) ----
  const bf16* Hf = &Hl[0][0][0];
  for (int p = tid; p < BM * 32; p += NTHR) {
    const int r = p >> 5, c = p & 31;
    float acc = bm[c];
    const bf16* hr2 = Hf + r * LDP;
    for (int k = 0; k < Hn; ++k) acc = fmaf((float)hr2[k], Wm[c * Hn + k], acc);
    const float mv = fsig(acc);
    Ml[r][c] = mv;
    Y[(size_t)Bt + (brow0 + r) * 32 + c] = mv;   // out_mmetric
  }
  __syncthreads();
  if (tid < BM) {
    float acc = bo[0];
#pragma unroll
    for (int c = 0; c < 32; ++c) acc = fmaf(Ml[tid][c], Wo[c], acc);
    Y[brow0 + tid] = fsig(acc);                  // out_mscore
  }
}

extern "C" void kernel_launch(void* const* d_in, const int* in_sizes, int n_in,
                              void* d_out, int out_size, void* d_ws, size_t ws_size,
                              hipStream_t stream) {
  const float* X   = (const float*)d_in[0];
  const float* Wih = (const float*)d_in[1];
  const float* Whh = (const float*)d_in[2];
  const float* bih = (const float*)d_in[3];
  const float* bhh = (const float*)d_in[4];
  const float* Wm  = (const float*)d_in[5];
  const float* bm  = (const float*)d_in[6];
  const float* Wo  = (const float*)d_in[7];
  const float* bo  = (const float*)d_in[8];

  const int B = in_sizes[0] / (Tn * Hn);   // 32768
  dim3 grid(B / BM), block(NTHR);
  gru_fused<<<grid, block, 0, stream>>>(X, Wih, Whh, bih, bhh, Wm, bm, Wo, bo,
                                        (float*)d_out, B);
}

// Round 6
// 624.644 us; speedup vs baseline: 1.8272x; 1.8272x over previous
//
#include <hip/hip_runtime.h>
#include <hip/hip_bf16.h>

#define Hn   89
#define Tn   120
#define BM   128
#define LDP  104   // bf16 pitch: 208B rows (16B-aligned); quad-balanced b128 reads
#define NTHR 768   // 12 waves = 6 j-slices x 2 row-halves; grid=256 -> 1 block/CU

using bf16   = __bf16;
using bf16x8 = __attribute__((ext_vector_type(8))) __bf16;
typedef __attribute__((ext_vector_type(4))) float f32x4;

__device__ __forceinline__ f32x4 ld4(const float* p) {   // 4B-aligned 16B load
  f32x4 v; __builtin_memcpy(&v, p, 16); return v;
}
__device__ __forceinline__ bf16x8 pack8(f32x4 a, f32x4 b) {
  bf16x8 r;
  r[0]=(bf16)a[0]; r[1]=(bf16)a[1]; r[2]=(bf16)a[2]; r[3]=(bf16)a[3];
  r[4]=(bf16)b[0]; r[5]=(bf16)b[1]; r[6]=(bf16)b[2]; r[7]=(bf16)b[3];
  return r;
}
__device__ __forceinline__ float fsig(float x) {
  return __builtin_amdgcn_rcpf(1.f + __builtin_amdgcn_exp2f(-1.44269504f * x));
}
__device__ __forceinline__ float ftanh(float x) {
  return 1.f - 2.f * __builtin_amdgcn_rcpf(1.f + __builtin_amdgcn_exp2f(2.88539008f * x));
}

// Persistent block: 128 rows x 120 steps, 12 waves (6 j-slices x 2 row-halves).
// One barrier/step. Iteration t: BAR; issue X(t+1)->regs; per mt {read frags
// from buf[t&1], MFMA, gates, write h(t+1)[mt] -> buf[t&1 ^1]}; commit X(t+1)
// -> buf[t&1 ^1]. Writes overlap compute; pre-barrier region is empty.
// H uses a per-row 16B-block XOR swizzle (block = (j>>3) ^ ((row>>2)&3)):
// h-writes hit 4 disjoint bank groups (conflict-free), reads stay b128.
// Biases folded via constant-1.0 column at k=89.
__global__ __launch_bounds__(NTHR, 3)
void gru_fused(const float* __restrict__ X,    // [B][T][89]
               const float* __restrict__ Wih,  // [267][89]
               const float* __restrict__ Whh,  // [267][89]
               const float* __restrict__ bih,  // [267]
               const float* __restrict__ bhh,  // [267]
               const float* __restrict__ Wm,   // [32][89]
               const float* __restrict__ bm,   // [32]
               const float* __restrict__ Wo,   // [32]
               const float* __restrict__ bo,   // [1]
               float* __restrict__ Y,          // [B] mscore | [B][32] mmetric
               int Bt)
{
  __shared__ __align__(16) bf16 Xl[2][BM][LDP];
  __shared__ __align__(16) bf16 Hl[2][BM][LDP];
  __shared__ float Ml[BM][32];

  const int tid  = threadIdx.x;
  const int lane = tid & 63;
  const int wv   = tid >> 6;       // 0..11
  const int jt   = wv >> 1;        // j-slice 0..5
  const int hf   = wv & 1;         // row half
  const int l15  = lane & 15;
  const int kg   = lane >> 4;      // 0..3
  const int j    = jt * 16 + l15;  // 0..95; j==89 = constant-1 column
  const bool jok = (j < Hn);
  const int swz  = (l15 >> 2) & 3; // read-side row swizzle selector
  const size_t brow0 = (size_t)blockIdx.x * BM;

  // ---- weights -> persistent register B-frags; k==89 carries biases ----
  bf16x8 Bf[3][2][3];  // [gate r/z/n][ih/hh][k-tile]
#pragma unroll
  for (int g = 0; g < 3; ++g)
#pragma unroll
    for (int s = 0; s < 2; ++s) {
      const float* W = s ? Whh : Wih;
#pragma unroll
      for (int kt = 0; kt < 3; ++kt) {
        bf16x8 f;
        const int k0 = kt * 32 + kg * 8;
#pragma unroll
        for (int e = 0; e < 8; ++e) {
          const int k = k0 + e;
          float v = 0.f;
          if (jok) {
            if (k < Hn) v = W[(size_t)(g * Hn + j) * Hn + k];
            else if (k == Hn) {           // pairs with the 1.0 at col 89
              if (g < 2) v = s ? 0.f : (bih[g * Hn + j] + bhh[g * Hn + j]);
              else       v = s ? bhh[2 * Hn + j] : bih[2 * Hn + j];
            }
          }
          f[e] = (bf16)v;
        }
        Bf[g][s][kt] = f;
      }
    }

  // ---- X staging: 128 rows x 12 chunks of 8 f32; exactly 2 chunks/thread ----
  int soff0, soff1, loff0, loff1;
  bool lst0, lst1;
  {
    const int p0 = tid, p1 = tid + NTHR;
    const int r0 = p0 / 12, s0 = p0 - r0 * 12;
    const int r1 = p1 / 12, s1 = p1 - r1 * 12;
    lst0 = (s0 == 11); lst1 = (s1 == 11);
    soff0 = r0 * (Tn * Hn) + s0 * 8;  loff0 = r0 * LDP + s0 * 8;
    soff1 = r1 * (Tn * Hn) + s1 * 8;  loff1 = r1 * LDP + s1 * 8;
  }
  const float* Xb2 = X + brow0 * (size_t)(Tn * Hn);
  f32x4 A0, B0, A1, B1;

  auto issue = [&](int toff) {
    const float* p0 = Xb2 + soff0 + toff;
    const float* p1 = Xb2 + soff1 + toff;
    if (lst0) { f32x4 a = {p0[0], 1.0f, 0.f, 0.f}; A0 = a; B0 = (f32x4){0.f,0.f,0.f,0.f}; }
    else      { A0 = ld4(p0); B0 = ld4(p0 + 4); }
    if (lst1) { f32x4 a = {p1[0], 1.0f, 0.f, 0.f}; A1 = a; B1 = (f32x4){0.f,0.f,0.f,0.f}; }
    else      { A1 = ld4(p1); B1 = ld4(p1 + 4); }
  };
  auto commit = [&](int plane) {
    *(bf16x8*)(&Xl[plane][0][0] + loff0) = pack8(A0, B0);
    *(bf16x8*)(&Xl[plane][0][0] + loff1) = pack8(A1, B1);
  };

  // ---- init H pads (both planes): col89=1.0, cols90..95=0 (swizzled blk 11) ----
  if (tid < 2 * BM) {
    const int pl = tid >> 7, r = tid & (BM - 1);
    bf16* hp = &Hl[pl][r][(size_t)((11 ^ ((r >> 2) & 3)) << 3)];
    hp[1] = (bf16)1.0f;                       // col 89
#pragma unroll
    for (int e = 2; e < 8; ++e) hp[e] = (bf16)0.f;  // cols 90..95
  }

  float hold[4][4];
#pragma unroll
  for (int mt = 0; mt < 4; ++mt)
#pragma unroll
    for (int q = 0; q < 4; ++q) hold[mt][q] = 0.f;

  // lane-constant LDS bases
  const int hswzcol = (((j >> 3) ^ kg) << 3) | (j & 7);
  bf16*       hwb = &Hl[0][0][0] + (hf * 64 + kg * 4) * LDP + hswzcol;
  const bf16* xrb = &Xl[0][0][0] + (hf * 64 + l15) * LDP + kg * 8;
  const bf16* hrb = &Hl[0][0][0] + (hf * 64 + l15) * LDP + ((kg ^ swz) << 3);
  const int bufo = BM * LDP;

  // ---- prologue: X(0) -> plane0, h(0)=0 -> plane0 ----
  issue(0);
  if (jok) {
#pragma unroll
    for (int mt = 0; mt < 4; ++mt)
#pragma unroll
      for (int q = 0; q < 4; ++q)
        hwb[(mt * 16 + q) * LDP] = (bf16)0.f;
  }
  commit(0);

  int toff = Hn;
  for (int t = 0; t < Tn; ++t) {
    const int b = t & 1;
    __syncthreads();                      // buf b now holds X(t), h(t)
    const bool pf = (t + 1 < Tn);
    if (pf) issue(toff);                  // X(t+1): flies under this step

    __builtin_amdgcn_s_setprio(1);
    const bf16* xr = xrb + b * bufo;
    const bf16* hr = hrb + b * bufo;
    bf16*       hw = hwb + (b ^ 1) * bufo;
#pragma unroll
    for (int mt = 0; mt < 4; ++mt) {
      f32x4 ar = {0,0,0,0}, az = {0,0,0,0}, ain = {0,0,0,0}, ahn = {0,0,0,0};
#pragma unroll
      for (int kt = 0; kt < 3; ++kt) {
        const bf16x8 ax = *(const bf16x8*)(xr + mt * 16 * LDP + kt * 32);
        const bf16x8 ah = *(const bf16x8*)(hr + mt * 16 * LDP + kt * 32);
        ar  = __builtin_amdgcn_mfma_f32_16x16x32_bf16(ax, Bf[0][0][kt], ar, 0, 0, 0);
        ar  = __builtin_amdgcn_mfma_f32_16x16x32_bf16(ah, Bf[0][1][kt], ar, 0, 0, 0);
        az  = __builtin_amdgcn_mfma_f32_16x16x32_bf16(ax, Bf[1][0][kt], az, 0, 0, 0);
        az  = __builtin_amdgcn_mfma_f32_16x16x32_bf16(ah, Bf[1][1][kt], az, 0, 0, 0);
        ain = __builtin_amdgcn_mfma_f32_16x16x32_bf16(ax, Bf[2][0][kt], ain, 0, 0, 0);
        ahn = __builtin_amdgcn_mfma_f32_16x16x32_bf16(ah, Bf[2][1][kt], ahn, 0, 0, 0);
      }
#pragma unroll
      for (int q = 0; q < 4; ++q) {
        const float r_ = fsig(ar[q]);
        const float z_ = fsig(az[q]);
        const float n_ = ftanh(ain[q] + r_ * ahn[q]);
        hold[mt][q] = n_ + z_ * (hold[mt][q] - n_);
      }
      if (jok) {                          // h(t+1)[mt] -> buf b^1, overlapped
#pragma unroll
        for (int q = 0; q < 4; ++q)
          hw[(mt * 16 + q) * LDP] = (bf16)hold[mt][q];
      }
    }
    __builtin_amdgcn_s_setprio(0);
    if (pf) { commit(b ^ 1); toff += Hn; }   // X(t+1) -> buf b^1
  }
  __syncthreads();   // h(120) writes (went to plane 0 during t=119) visible

  // ---- epilogue: metric_fc (89->32, sigmoid), output_fc (32->1, sigmoid) ----
  for (int p = tid; p < BM * 32; p += NTHR) {
    const int r = p >> 5, c = p & 31;
    const int rs = (r >> 2) & 3;
    const bf16* hr2 = &Hl[0][r][0];
    const float* wrow = Wm + c * Hn;
    float acc = bm[c];
#pragma unroll 4
    for (int cb = 0; cb < 11; ++cb) {
      const bf16x8 hv = *(const bf16x8*)(hr2 + ((cb ^ rs) << 3));
      const f32x4 wa = ld4(wrow + cb * 8);
      const f32x4 wb = ld4(wrow + cb * 8 + 4);
      acc = fmaf((float)hv[0], wa[0], acc); acc = fmaf((float)hv[1], wa[1], acc);
      acc = fmaf((float)hv[2], wa[2], acc); acc = fmaf((float)hv[3], wa[3], acc);
      acc = fmaf((float)hv[4], wb[0], acc); acc = fmaf((float)hv[5], wb[1], acc);
      acc = fmaf((float)hv[6], wb[2], acc); acc = fmaf((float)hv[7], wb[3], acc);
    }
    acc = fmaf((float)hr2[(11 ^ rs) << 3], wrow[88], acc);   // k=88
    const float mv = fsig(acc);
    Ml[r][c] = mv;
    Y[(size_t)Bt + (brow0 + r) * 32 + c] = mv;   // out_mmetric
  }
  __syncthreads();
  if (tid < BM) {
    float acc = bo[0];
#pragma unroll
    for (int c = 0; c < 32; ++c) acc = fmaf(Ml[tid][c], Wo[c], acc);
    Y[brow0 + tid] = fsig(acc);                  // out_mscore
  }
}

extern "C" void kernel_launch(void* const* d_in, const int* in_sizes, int n_in,
                              void* d_out, int out_size, void* d_ws, size_t ws_size,
                              hipStream_t stream) {
  const float* X   = (const float*)d_in[0];
  const float* Wih = (const float*)d_in[1];
  const float* Whh = (const float*)d_in[2];
  const float* bih = (const float*)d_in[3];
  const float* bhh = (const float*)d_in[4];
  const float* Wm  = (const float*)d_in[5];
  const float* bm  = (const float*)d_in[6];
  const float* Wo  = (const float*)d_in[7];
  const float* bo  = (const float*)d_in[8];

  const int B = in_sizes[0] / (Tn * Hn);   // 32768
  dim3 grid(B / BM), block(NTHR);
  gru_fused<<<grid, block, 0, stream>>>(X, Wih, Whh, bih, bhh, Wm, bm, Wo, bo,
                                        (float*)d_out, B);
}